// Round 1
// baseline (195.908 us; speedup 1.0000x reference)
//
#include <hip/hip_runtime.h>

// Y = X @ Q where Q is a 512x512 permutation (one-hot) matrix.
// Equivalent to a column gather: Y[n][j] = X[n][map[j]], map[j] = argmax_d Q[d][j].

#define DCOLS 512
#define ROWS_PER_BLOCK 8

__global__ __launch_bounds__(256)
void build_map_kernel(const float* __restrict__ Q, int* __restrict__ map) {
    int idx = blockIdx.x * 256 + threadIdx.x;   // idx = d*512 + j, covers 512*512
    if (idx < DCOLS * DCOLS) {
        if (Q[idx] > 0.5f) {
            map[idx & (DCOLS - 1)] = idx >> 9;  // map[j] = d
        }
    }
}

__global__ __launch_bounds__(256)
void permute_gather_kernel(const float* __restrict__ X,
                           const int* __restrict__ map,
                           float* __restrict__ out) {
    __shared__ float lds[ROWS_PER_BLOCK * DCOLS];   // 16 KiB

    const int t = threadIdx.x;
    const long long n0 = (long long)blockIdx.x * ROWS_PER_BLOCK;

    // Coalesced float4 staging of 8 rows into LDS.
    const float4* src = (const float4*)(X + n0 * DCOLS);
    float4* l4 = (float4*)lds;
    #pragma unroll
    for (int i = 0; i < (ROWS_PER_BLOCK * DCOLS / 4) / 256; ++i) {   // 4 iters
        l4[t + i * 256] = src[t + i * 256];
    }
    __syncthreads();

    // Each thread owns 4 consecutive output columns (j = 4*jg .. 4*jg+3) for
    // half the rows. Gather from LDS, write one coalesced float4.
    const int jg   = t & 127;   // float4 column-group within a row
    const int half = t >> 7;    // which row of each pair
    const int4 m = ((const int4*)map)[jg];

    #pragma unroll
    for (int rp = 0; rp < ROWS_PER_BLOCK / 2; ++rp) {
        const int row = rp * 2 + half;
        float4 o;
        o.x = lds[row * DCOLS + m.x];
        o.y = lds[row * DCOLS + m.y];
        o.z = lds[row * DCOLS + m.z];
        o.w = lds[row * DCOLS + m.w];
        ((float4*)(out + (n0 + row) * DCOLS))[jg] = o;
    }
}

extern "C" void kernel_launch(void* const* d_in, const int* in_sizes, int n_in,
                              void* d_out, int out_size, void* d_ws, size_t ws_size,
                              hipStream_t stream) {
    const float* X = (const float*)d_in[0];
    const float* Q = (const float*)d_in[1];
    float* out = (float*)d_out;
    int* map = (int*)d_ws;   // 512 ints = 2 KiB scratch

    const int N = in_sizes[0] / DCOLS;   // 262144

    // 1) Build the column->source-row map from Q (deterministic, every call).
    build_map_kernel<<<(DCOLS * DCOLS + 255) / 256, 256, 0, stream>>>(Q, map);

    // 2) Gather.
    permute_gather_kernel<<<N / ROWS_PER_BLOCK, 256, 0, stream>>>(X, map, out);
}